// Round 1
// baseline (408.116 us; speedup 1.0000x reference)
//
#include <hip/hip_runtime.h>
#include <hip/hip_bf16.h>
#include <math.h>

typedef __attribute__((ext_vector_type(8))) short bf16x8;
typedef __attribute__((ext_vector_type(4))) float f32x4;

#define DEVI __device__ __forceinline__

DEVI unsigned short f2bf(float f) {
  unsigned int u = __builtin_bit_cast(unsigned int, f);
  unsigned int r = (u + 0x7fffu + ((u >> 16) & 1u)) >> 16;
  return (unsigned short)r;
}
DEVI float bf2f(unsigned int h) {
  unsigned int u = (h & 0xffffu) << 16;
  return __builtin_bit_cast(float, u);
}

// ---------------- prep: Wo (192,128,3,3) f32 -> wo_t[dydx][o][c] bf16 ----------------
__global__ __launch_bounds__(256) void k_prep_wo(const float* __restrict__ Wo,
                                                 unsigned short* __restrict__ wo_t) {
  int i = blockIdx.x * 256 + threadIdx.x;
  if (i >= 9 * 192 * 128) return;
  int c = i & 127;
  int rem = i >> 7;            // dydx*192 + o
  int o = rem % 192;
  int dydx = rem / 192;
  wo_t[i] = f2bf(Wo[(o * 128 + c) * 9 + dydx]);
}

// ---------------- prep: h f32 -> xcat channels 64..127 bf16 ----------------
__global__ __launch_bounds__(256) void k_prep_h(const float* __restrict__ h,
                                                unsigned short* __restrict__ xcat) {
  int i = blockIdx.x * 256 + threadIdx.x;   // handles 4 elems
  int base = i * 4;                          // flat index into h  [n][c][s]
  int n = base >> 18;
  int r = base & 262143;
  int c = r >> 12;
  int s = r & 4095;
  float4 v = *(const float4*)(h + base);
  unsigned short tmp[4] = {f2bf(v.x), f2bf(v.y), f2bf(v.z), f2bf(v.w)};
  *(unsigned long long*)(xcat + (((size_t)n * 128 + 64 + c) << 12) + s) =
      *(const unsigned long long*)tmp;
}

// ---------------- proj: 1x1 convs -> q/k/km ([n][s][c]) and v/vm ([n][c][s]) ----------------
__global__ __launch_bounds__(256) void k_proj(
    const float* __restrict__ h, const float* __restrict__ m,
    const float* __restrict__ Wh, const float* __restrict__ bh,
    const float* __restrict__ Wm, const float* __restrict__ bm,
    unsigned short* __restrict__ qb, unsigned short* __restrict__ kb,
    unsigned short* __restrict__ kmb, unsigned short* __restrict__ vb,
    unsigned short* __restrict__ vmb) {
  __shared__ float xt[64][32];   // [c][s]
  __shared__ float wt[64][68];   // [c][o], padded row (8-way max on write)
  const int t = threadIdx.x;
  const int st0 = blockIdx.x * 32;
  const int n = blockIdx.y;
  const int ob = blockIdx.z;     // 0:hq 1:hk 2:hv 3:mk 4:mv
  const float* __restrict__ x = (ob < 3) ? h : m;
  const float* __restrict__ W = (ob < 3) ? Wh : Wm;
  const float* __restrict__ bias = (ob < 3) ? bh : bm;
  const int obase = (ob < 3) ? ob * 64 : (ob - 3) * 64;

  {
    const int s = t & 31, cq = t >> 5;
    const float* src = x + (((size_t)n * 64) << 12) + st0 + s;
    #pragma unroll
    for (int r = 0; r < 8; ++r) { int c = cq + 8 * r; xt[c][s] = src[(size_t)c << 12]; }
  }
  {
    const int c = t & 63, oq = t >> 6;
    #pragma unroll
    for (int r = 0; r < 16; ++r) {
      int o = oq + 4 * r;
      wt[c][o] = W[(size_t)(obase + o) * 64 + c];
    }
  }
  __syncthreads();

  if (ob == 0 || ob == 1 || ob == 3) {
    // variant A: 8 consecutive out-channels x 1 position -> [s][c] layout
    const int og = t & 7, s = t >> 3;
    float acc[8];
    #pragma unroll
    for (int k = 0; k < 8; ++k) acc[k] = bias[obase + og * 8 + k];
    for (int c = 0; c < 64; ++c) {
      const float xv = xt[c][s];
      const float4 wa = *(const float4*)&wt[c][og * 8];
      const float4 wb = *(const float4*)&wt[c][og * 8 + 4];
      acc[0] += wa.x * xv; acc[1] += wa.y * xv; acc[2] += wa.z * xv; acc[3] += wa.w * xv;
      acc[4] += wb.x * xv; acc[5] += wb.y * xv; acc[6] += wb.z * xv; acc[7] += wb.w * xv;
    }
    const float scale = (ob == 0) ? 0.125f : 1.0f;   // fold 1/sqrt(64) into q
    unsigned short* dst = (ob == 0) ? qb : (ob == 1 ? kb : kmb);
    unsigned short tmp[8];
    #pragma unroll
    for (int k = 0; k < 8; ++k) tmp[k] = f2bf(acc[k] * scale);
    *(uint4*)(dst + (((size_t)n * 4096 + st0 + s) << 6) + og * 8) = *(const uint4*)tmp;
  } else {
    // variant B: 1 out-channel x 8 positions -> [c][s] layout
    const int o = t & 63, sg = t >> 6;
    float acc[8];
    const float bv = bias[obase + o];
    #pragma unroll
    for (int k = 0; k < 8; ++k) acc[k] = bv;
    for (int c = 0; c < 64; ++c) {
      const float wv = wt[c][o];
      #pragma unroll
      for (int u = 0; u < 8; ++u) acc[u] += wv * xt[c][sg * 8 + u];
    }
    unsigned short* dst = (ob == 2) ? vb : vmb;
    unsigned short tmp[8];
    #pragma unroll
    for (int k = 0; k < 8; ++k) tmp[k] = f2bf(acc[k]);
    *(uint4*)(dst + (((size_t)n * 64 + o) << 12) + st0 + sg * 8) = *(const uint4*)tmp;
  }
}

// ---------------- flash attention: S=4096, d=64, two selectors ----------------
__global__ __launch_bounds__(256) void k_attn(
    const unsigned short* __restrict__ qb, const unsigned short* __restrict__ kb,
    const unsigned short* __restrict__ kmb, const unsigned short* __restrict__ vb,
    const unsigned short* __restrict__ vmb, unsigned short* __restrict__ zcat) {
  __shared__ unsigned short Kt[4096];     // [key][c] XOR-swizzled
  __shared__ unsigned short Vt[4096];     // [c][key] XOR-swizzled
  __shared__ unsigned short Pl[4][1024];  // per-wave [q][key] XOR-swizzled
  const int t = threadIdx.x;
  const int w = t >> 6, l = t & 63;
  const int lg = l >> 4, ll = l & 15;
  const int qt = blockIdx.x, n = blockIdx.y, sel = blockIdx.z;
  const unsigned short* __restrict__ Ksrc = sel ? kmb : kb;
  const unsigned short* __restrict__ Vsrc = sel ? vmb : vb;

  bf16x8 qf0, qf1;
  {
    const int sq = qt * 64 + w * 16 + ll;
    const unsigned short* qp = qb + (((size_t)n * 4096 + sq) << 6) + lg * 8;
    qf0 = *(const bf16x8*)(qp);
    qf1 = *(const bf16x8*)(qp + 32);
  }
  f32x4 Oacc[4];
  float mrun[4], lrun[4];
  #pragma unroll
  for (int j = 0; j < 4; ++j) {
    mrun[j] = -1e30f; lrun[j] = 0.f;
    #pragma unroll
    for (int ct = 0; ct < 4; ++ct) Oacc[ct][j] = 0.f;
  }
  const unsigned short* kbase = Ksrc + ((size_t)n << 18);
  const unsigned short* vbase = Vsrc + ((size_t)n << 18);
  char* KtB = (char*)Kt;
  char* VtB = (char*)Vt;
  char* PlB = (char*)&Pl[w][0];

  for (int kt = 0; kt < 64; ++kt) {
    __syncthreads();
    #pragma unroll
    for (int r = 0; r < 2; ++r) {
      const int chunk = t + 256 * r;
      const int row = chunk >> 3, cp = chunk & 7;
      uint4 dk = *(const uint4*)(kbase + (((size_t)(kt * 64 + row)) << 6) + cp * 8);
      *(uint4*)(KtB + ((row * 128 + cp * 16) ^ ((row & 7) << 4))) = dk;
      uint4 dv = *(const uint4*)(vbase + (((size_t)row) << 12) + kt * 64 + cp * 8);
      *(uint4*)(VtB + ((row * 128 + cp * 16) ^ ((row & 7) << 4))) = dv;
    }
    __syncthreads();

    f32x4 sc[4];
    #pragma unroll
    for (int ct = 0; ct < 4; ++ct)
      #pragma unroll
      for (int j = 0; j < 4; ++j) sc[ct][j] = 0.f;
    #pragma unroll
    for (int k32 = 0; k32 < 2; ++k32) {
      const bf16x8 a = k32 ? qf1 : qf0;
      #pragma unroll
      for (int ct = 0; ct < 4; ++ct) {
        const int key = ct * 16 + ll;
        const bf16x8 b = *(const bf16x8*)(KtB +
            ((key * 128 + k32 * 64 + lg * 16) ^ ((key & 7) << 4)));
        sc[ct] = __builtin_amdgcn_mfma_f32_16x16x32_bf16(a, b, sc[ct], 0, 0, 0);
      }
    }
    // online softmax, per accumulator register j (query = lg*4 + j)
    #pragma unroll
    for (int j = 0; j < 4; ++j) {
      float rmax = fmaxf(fmaxf(sc[0][j], sc[1][j]), fmaxf(sc[2][j], sc[3][j]));
      rmax = fmaxf(rmax, __shfl_xor(rmax, 1));
      rmax = fmaxf(rmax, __shfl_xor(rmax, 2));
      rmax = fmaxf(rmax, __shfl_xor(rmax, 4));
      rmax = fmaxf(rmax, __shfl_xor(rmax, 8));
      const float nm = fmaxf(mrun[j], rmax);
      const float alpha = __expf(mrun[j] - nm);
      mrun[j] = nm;
      float pv[4];
      float rs = 0.f;
      #pragma unroll
      for (int ct = 0; ct < 4; ++ct) { pv[ct] = __expf(sc[ct][j] - nm); rs += pv[ct]; }
      rs += __shfl_xor(rs, 1); rs += __shfl_xor(rs, 2);
      rs += __shfl_xor(rs, 4); rs += __shfl_xor(rs, 8);
      lrun[j] = lrun[j] * alpha + rs;
      #pragma unroll
      for (int ct = 0; ct < 4; ++ct) Oacc[ct][j] *= alpha;
      const int q = lg * 4 + j;
      const int swz = (q & 7) << 4;
      #pragma unroll
      for (int ct = 0; ct < 4; ++ct)
        *(unsigned short*)(PlB + ((q * 128 + (ct * 16 + ll) * 2) ^ swz)) = f2bf(pv[ct]);
    }
    // P @ V
    #pragma unroll
    for (int k32 = 0; k32 < 2; ++k32) {
      const bf16x8 a = *(const bf16x8*)(PlB +
          ((ll * 128 + k32 * 64 + lg * 16) ^ ((ll & 7) << 4)));
      #pragma unroll
      for (int ct = 0; ct < 4; ++ct) {
        const int c = ct * 16 + ll;
        const bf16x8 b = *(const bf16x8*)(VtB +
            ((c * 128 + k32 * 64 + lg * 16) ^ ((c & 7) << 4)));
        Oacc[ct] = __builtin_amdgcn_mfma_f32_16x16x32_bf16(a, b, Oacc[ct], 0, 0, 0);
      }
    }
  }
  // epilogue: zcat[n][s][sel*64 + c]
  #pragma unroll
  for (int j = 0; j < 4; ++j) {
    const float inv = 1.0f / lrun[j];
    const int srow = qt * 64 + w * 16 + lg * 4 + j;
    #pragma unroll
    for (int ct = 0; ct < 4; ++ct) {
      const int c = sel * 64 + ct * 16 + ll;
      zcat[(((size_t)n * 4096 + srow) << 7) + c] = f2bf(Oacc[ct][j] * inv);
    }
  }
}

// ---------------- Z = Wz @ Zcat + bz -> xcat channels 0..63 (bf16) ----------------
__global__ __launch_bounds__(256) void k_zgemm(
    const unsigned short* __restrict__ zcat, const float* __restrict__ Wz,
    const float* __restrict__ bz, unsigned short* __restrict__ xcat) {
  __shared__ float zt[32][132];   // [s][k] f32, padded
  __shared__ float wzt[128][68];  // [k][cz] padded
  const int t = threadIdx.x;
  const int st0 = blockIdx.x * 32, n = blockIdx.y;
  {
    #pragma unroll
    for (int r = 0; r < 2; ++r) {
      const int chunk = t + 256 * r;
      const int s = chunk >> 4, kp = chunk & 15;
      const uint4 d = *(const uint4*)(zcat + (((size_t)n * 4096 + st0 + s) << 7) + kp * 8);
      const unsigned int u[4] = {d.x, d.y, d.z, d.w};
      #pragma unroll
      for (int e = 0; e < 4; ++e) {
        zt[s][kp * 8 + 2 * e]     = bf2f(u[e]);
        zt[s][kp * 8 + 2 * e + 1] = bf2f(u[e] >> 16);
      }
    }
  }
  {
    const int k = t & 127, czq = t >> 7;
    #pragma unroll
    for (int r = 0; r < 32; ++r) {
      const int cz = czq + 2 * r;
      wzt[k][cz] = Wz[((size_t)cz << 7) + k];
    }
  }
  __syncthreads();
  const int cz = t & 63, sg = t >> 6;
  float acc[8];
  const float bv = bz[cz];
  #pragma unroll
  for (int u = 0; u < 8; ++u) acc[u] = bv;
  for (int k = 0; k < 128; ++k) {
    const float wv = wzt[k][cz];
    #pragma unroll
    for (int u = 0; u < 8; ++u) acc[u] += wv * zt[sg * 8 + u][k];
  }
  unsigned short tmp[8];
  #pragma unroll
  for (int u = 0; u < 8; ++u) tmp[u] = f2bf(acc[u]);
  *(uint4*)(xcat + (((size_t)n * 128 + cz) << 12) + st0 + sg * 8) = *(const uint4*)tmp;
}

// ---------------- 3x3 conv (MFMA) + gates ----------------
__global__ __launch_bounds__(256) void k_conv(
    const unsigned short* __restrict__ xcat, const unsigned short* __restrict__ wo_t,
    const float* __restrict__ bo, const float* __restrict__ m_in,
    float* __restrict__ out) {
  __shared__ unsigned short xt[3][66][40];   // [dy][w+1][c] (c padded 32->40)
  const int t = threadIdx.x;
  const int wv = t >> 6, l = t & 63, lg = l >> 4, ll = l & 15;
  const int y = blockIdx.x, n = blockIdx.y;
  f32x4 acc[3][4];
  #pragma unroll
  for (int ot = 0; ot < 3; ++ot)
    #pragma unroll
    for (int ct = 0; ct < 4; ++ct)
      #pragma unroll
      for (int e = 0; e < 4; ++e) acc[ot][ct][e] = 0.f;

  for (int cb = 0; cb < 4; ++cb) {
    __syncthreads();
    {
      if (t < 192) {
        const int side = t / 96, rr = t % 96;
        xt[rr >> 5][side * 65][rr & 31] = 0;
      }
      const int wx = t & 63, q = t >> 6;
      #pragma unroll
      for (int r = 0; r < 24; ++r) {
        const int idx = q + 4 * r;        // 0..95 = (dy, c)
        const int c = idx & 31, dy = idx >> 5;
        const int yin = y + dy - 1;
        unsigned short vv = 0;
        if (yin >= 0 && yin < 64)
          vv = xcat[(((size_t)n * 128 + cb * 32 + c) << 12) + yin * 64 + wx];
        xt[dy][wx + 1][c] = vv;
      }
    }
    __syncthreads();
    #pragma unroll
    for (int dy = 0; dy < 3; ++dy) {
      #pragma unroll
      for (int dx = 0; dx < 3; ++dx) {
        bf16x8 bfr[4];
        #pragma unroll
        for (int ct = 0; ct < 4; ++ct)
          bfr[ct] = *(const bf16x8*)&xt[dy][ct * 16 + ll + dx][lg * 8];
        #pragma unroll
        for (int ot = 0; ot < 3; ++ot) {
          const int o = (wv + ot * 4) * 16 + ll;
          const bf16x8 afr = *(const bf16x8*)(wo_t +
              (((size_t)(dy * 3 + dx) * 192 + o) << 7) + cb * 32 + lg * 8);
          #pragma unroll
          for (int ct = 0; ct < 4; ++ct)
            acc[ot][ct] = __builtin_amdgcn_mfma_f32_16x16x32_bf16(afr, bfr[ct], acc[ot][ct], 0, 0, 0);
        }
      }
    }
  }
  // gates: wave wv holds i (tile wv), g (tile wv+4), o (tile wv+8) for channels wv*16..+16
  #pragma unroll
  for (int ct = 0; ct < 4; ++ct) {
    #pragma unroll
    for (int r = 0; r < 4; ++r) {
      const int c = wv * 16 + lg * 4 + r;
      const int sx = ct * 16 + ll;
      const size_t pix = (((size_t)n * 64 + c) << 12) + y * 64 + sx;
      const float yi = acc[0][ct][r] + bo[c];
      const float yg = acc[1][ct][r] + bo[64 + c];
      const float yo = acc[2][ct][r] + bo[128 + c];
      const float iv = 1.f / (1.f + __expf(-yi));
      const float gv = tanhf(yg);
      const float ov = 1.f / (1.f + __expf(-yo));
      const float mo = m_in[pix];
      const float mn = iv * gv + (1.f - iv) * mo;
      out[pix] = ov * mn;              // h_next
      out[pix + 2097152] = mn;         // m_next
    }
  }
}

extern "C" void kernel_launch(void* const* d_in, const int* in_sizes, int n_in,
                              void* d_out, int out_size, void* d_ws, size_t ws_size,
                              hipStream_t stream) {
  const float* h  = (const float*)d_in[0];
  const float* m  = (const float*)d_in[1];
  const float* Wh = (const float*)d_in[2];
  const float* bh = (const float*)d_in[3];
  const float* Wm = (const float*)d_in[4];
  const float* bm = (const float*)d_in[5];
  const float* Wz = (const float*)d_in[6];
  const float* bz = (const float*)d_in[7];
  const float* Wo = (const float*)d_in[8];
  const float* bo = (const float*)d_in[9];
  float* out = (float*)d_out;

  unsigned short* ws  = (unsigned short*)d_ws;
  unsigned short* qbf  = ws;                    // [n][s][64] bf16, pre-scaled by 1/8
  unsigned short* kbf  = qbf + 2097152;         // [n][s][64]
  unsigned short* kmbf = kbf + 2097152;         // [n][s][64]
  unsigned short* vbf  = kmbf + 2097152;        // [n][64][s]
  unsigned short* vmbf = vbf + 2097152;         // [n][64][s]
  unsigned short* zcat = vmbf + 2097152;        // [n][s][128]
  unsigned short* xcat = zcat + 4194304;        // [n][128][s]  (ch0-63 Z, ch64-127 h)
  unsigned short* wot  = xcat + 4194304;        // [dydx][192][128]

  hipLaunchKernelGGL(k_prep_wo, dim3(864), dim3(256), 0, stream, Wo, wot);
  hipLaunchKernelGGL(k_prep_h, dim3(2048), dim3(256), 0, stream, h, xcat);
  hipLaunchKernelGGL(k_proj, dim3(128, 8, 5), dim3(256), 0, stream,
                     h, m, Wh, bh, Wm, bm, qbf, kbf, kmbf, vbf, vmbf);
  hipLaunchKernelGGL(k_attn, dim3(64, 8, 2), dim3(256), 0, stream,
                     qbf, kbf, kmbf, vbf, vmbf, zcat);
  hipLaunchKernelGGL(k_zgemm, dim3(128, 8), dim3(256), 0, stream, zcat, Wz, bz, xcat);
  hipLaunchKernelGGL(k_conv, dim3(64, 8), dim3(256), 0, stream, xcat, wot, bo, m, out);
}